// Round 8
// baseline (217.314 us; speedup 1.0000x reference)
//
#include <hip/hip_runtime.h>
#include <hip/hip_bf16.h>

// ---------------------------------------------------------------------------
// MultiHeadedMaskedSelfAttention (B=2,T=2048,C=768,H=12,D=64).
// I/O: float32. Compute: bf16 MFMA with hi/lo compensation on the
// softmax-critical path (x->Q/K and Q.K^T), plain bf16 elsewhere.
// attn_fwd v7: swapped-operand in-register softmax (v6, verified) +
// FLAT WAVES: each wave runs two sequential single-fragment flash passes
// over the pair {f, 127-f} -> exactly 33 tile-units per wave, 768 blocks
// x 128 thr = 3 blocks/CU exactly, 6 waves/CU sustained.
// (Round-3's pairing failure was a double x8 scale, not the mapping.)
// ---------------------------------------------------------------------------

typedef float f32x4 __attribute__((ext_vector_type(4)));
typedef short s16x8 __attribute__((ext_vector_type(8)));

#define MFMA(a, b, c) __builtin_amdgcn_mfma_f32_16x16x32_bf16((a), (b), (c), 0, 0, 0)

constexpr int Bb = 2, Tt = 2048, Cc = 768, Hh = 12, Dd = 64;
constexpr int Mm = Bb * Tt;   // 4096
constexpr int BH = Bb * Hh;   // 24

__device__ __forceinline__ void gload16(const void* g, void* l) {
  __builtin_amdgcn_global_load_lds((const __attribute__((address_space(1))) void*)g,
                                   (__attribute__((address_space(3))) void*)l, 16, 0, 0);
}

__device__ __forceinline__ short f2bfbits(float f) {
  __hip_bfloat16 h = __float2bfloat16(f);
  return __builtin_bit_cast(short, h);
}
__device__ __forceinline__ float bf2f(short s) {
  __hip_bfloat16 h = __builtin_bit_cast(__hip_bfloat16, s);
  return __bfloat162float(h);
}
__device__ __forceinline__ unsigned int packbf2(float a, float b) {
  return (unsigned int)(unsigned short)f2bfbits(a) |
         ((unsigned int)(unsigned short)f2bfbits(b) << 16);
}

// ---------------------------------------------------------------------------
// prep_x: x f32 [4096][768] -> Xhi, Xlo bf16. grid(1536), 256 thr, 8 elts/thr.
// ---------------------------------------------------------------------------
__global__ __launch_bounds__(256) void prep_x(const float* __restrict__ x,
                                              __hip_bfloat16* __restrict__ xhi,
                                              __hip_bfloat16* __restrict__ xlo) {
  const size_t i = ((size_t)blockIdx.x * 256 + threadIdx.x) * 8;
  float4 a = *reinterpret_cast<const float4*>(x + i);
  float4 b = *reinterpret_cast<const float4*>(x + i + 4);
  float v[8] = {a.x, a.y, a.z, a.w, b.x, b.y, b.z, b.w};
  s16x8 hi, lo;
#pragma unroll
  for (int j = 0; j < 8; ++j) {
    short h = f2bfbits(v[j]);
    hi[j] = h;
    lo[j] = f2bfbits(v[j] - bf2f(h));
  }
  *reinterpret_cast<s16x8*>((short*)xhi + i) = hi;
  *reinterpret_cast<s16x8*>((short*)xlo + i) = lo;
}

// ---------------------------------------------------------------------------
// prep_w: f32 [768][768] -> transposed bf16. z=0: wq (hi+lo), z=1: wk (hi+lo),
// z=2: wv (hi), z=3: linear (hi). grid (12,12,4), 256 thr, 64x64 tiles.
// ---------------------------------------------------------------------------
__global__ __launch_bounds__(256) void prep_w(
    const float* __restrict__ s0, const float* __restrict__ s1,
    const float* __restrict__ s2, const float* __restrict__ s3,
    __hip_bfloat16* __restrict__ h0, __hip_bfloat16* __restrict__ l0,
    __hip_bfloat16* __restrict__ h1, __hip_bfloat16* __restrict__ l1,
    __hip_bfloat16* __restrict__ h2, __hip_bfloat16* __restrict__ h3) {
  const float* src;
  __hip_bfloat16 *dh, *dl = nullptr;
  switch (blockIdx.z) {
    case 0: src = s0; dh = h0; dl = l0; break;
    case 1: src = s1; dh = h1; dl = l1; break;
    case 2: src = s2; dh = h2; break;
    default: src = s3; dh = h3; break;
  }
  __shared__ float tile[64][65];
  const int r0 = blockIdx.y * 64, c0 = blockIdx.x * 64;
  const int tid = threadIdx.x;
  const int rr = tid >> 4, c4 = (tid & 15) * 4;
#pragma unroll
  for (int it = 0; it < 4; ++it) {
    float4 v = *reinterpret_cast<const float4*>(src + (size_t)(r0 + rr + it * 16) * Cc + c0 + c4);
    tile[rr + it * 16][c4 + 0] = v.x;
    tile[rr + it * 16][c4 + 1] = v.y;
    tile[rr + it * 16][c4 + 2] = v.z;
    tile[rr + it * 16][c4 + 3] = v.w;
  }
  __syncthreads();
#pragma unroll
  for (int it = 0; it < 2; ++it) {
    const int id = tid + it * 256;          // 0..511
    const int n = id >> 3, ch = (id & 7) * 8;
    s16x8 hi, lo;
#pragma unroll
    for (int j = 0; j < 8; ++j) {
      float v = tile[ch + j][n];
      short h = f2bfbits(v);
      hi[j] = h;
      lo[j] = f2bfbits(v - bf2f(h));
    }
    *reinterpret_cast<s16x8*>(dh + (size_t)(c0 + n) * Cc + r0 + ch) = hi;
    if (dl) *reinterpret_cast<s16x8*>(dl + (size_t)(c0 + n) * Cc + r0 + ch) = lo;
  }
}

// ---------------------------------------------------------------------------
// 128x128 GEMM cores. A[M,K] * Bt[N,K]^T, K=768, BK=32, 4 waves.
// ---------------------------------------------------------------------------
__device__ __forceinline__ void gemm128_core(const __hip_bfloat16* __restrict__ A,
                                             const __hip_bfloat16* __restrict__ Bt,
                                             int m0, int n0,
                                             short* ldsA, short* ldsB,
                                             f32x4 acc[4][4]) {
  const int tid = threadIdx.x;
  const int w = tid >> 6, l = tid & 63;
  const int wr = w >> 1, wc = w & 1;
  const int srow = l >> 2;
  const int scol = (l & 3) << 3;

  for (int kt = 0; kt < Cc / 32; ++kt) {
    const int kk = kt << 5;
#pragma unroll
    for (int i = 0; i < 2; ++i) {
      const int r = (w << 5) + (i << 4);
      gload16(A + (size_t)(m0 + r + srow) * Cc + kk + scol, ldsA + r * 32);
      gload16(Bt + (size_t)(n0 + r + srow) * Cc + kk + scol, ldsB + r * 32);
    }
    __syncthreads();
    s16x8 af[4], bfr[4];
#pragma unroll
    for (int i = 0; i < 4; ++i) {
      af[i]  = *reinterpret_cast<const s16x8*>(ldsA + ((wr << 6) + (i << 4) + (l & 15)) * 32 + ((l >> 4) << 3));
      bfr[i] = *reinterpret_cast<const s16x8*>(ldsB + ((wc << 6) + (i << 4) + (l & 15)) * 32 + ((l >> 4) << 3));
    }
#pragma unroll
    for (int i = 0; i < 4; ++i)
#pragma unroll
      for (int j = 0; j < 4; ++j)
        acc[i][j] = MFMA(af[i], bfr[j], acc[i][j]);
    __syncthreads();
  }
}

// hi/lo compensated: acc += Ahi*Bhi + (lo ? Ahi*Blo + Alo*Bhi : 0)
__device__ __forceinline__ void gemm128_hilo(
    const __hip_bfloat16* __restrict__ Ahi, const __hip_bfloat16* __restrict__ Alo,
    const __hip_bfloat16* __restrict__ Bhi, const __hip_bfloat16* __restrict__ Blo,
    bool lo, int m0, int n0, short* lds, f32x4 acc[4][4]) {
  short* ldsAh = lds;
  short* ldsAl = lds + 4096;
  short* ldsBh = lds + 8192;
  short* ldsBl = lds + 12288;
  const int tid = threadIdx.x;
  const int w = tid >> 6, l = tid & 63;
  const int wr = w >> 1, wc = w & 1;
  const int srow = l >> 2;
  const int scol = (l & 3) << 3;

  for (int kt = 0; kt < Cc / 32; ++kt) {
    const int kk = kt << 5;
#pragma unroll
    for (int i = 0; i < 2; ++i) {
      const int r = (w << 5) + (i << 4);
      const size_t aoff = (size_t)(m0 + r + srow) * Cc + kk + scol;
      const size_t boff = (size_t)(n0 + r + srow) * Cc + kk + scol;
      gload16(Ahi + aoff, ldsAh + r * 32);
      gload16(Bhi + boff, ldsBh + r * 32);
      if (lo) {
        gload16(Alo + aoff, ldsAl + r * 32);
        gload16(Blo + boff, ldsBl + r * 32);
      }
    }
    __syncthreads();
    s16x8 ah[4], bh[4], al[4], bl[4];
#pragma unroll
    for (int i = 0; i < 4; ++i) {
      const int ao = ((wr << 6) + (i << 4) + (l & 15)) * 32 + ((l >> 4) << 3);
      const int bo = ((wc << 6) + (i << 4) + (l & 15)) * 32 + ((l >> 4) << 3);
      ah[i] = *reinterpret_cast<const s16x8*>(ldsAh + ao);
      bh[i] = *reinterpret_cast<const s16x8*>(ldsBh + bo);
      if (lo) {
        al[i] = *reinterpret_cast<const s16x8*>(ldsAl + ao);
        bl[i] = *reinterpret_cast<const s16x8*>(ldsBl + bo);
      }
    }
#pragma unroll
    for (int i = 0; i < 4; ++i)
#pragma unroll
      for (int j = 0; j < 4; ++j)
        acc[i][j] = MFMA(ah[i], bh[j], acc[i][j]);
    if (lo) {
#pragma unroll
      for (int i = 0; i < 4; ++i)
#pragma unroll
        for (int j = 0; j < 4; ++j) {
          acc[i][j] = MFMA(ah[i], bl[j], acc[i][j]);
          acc[i][j] = MFMA(al[i], bh[j], acc[i][j]);
        }
    }
    __syncthreads();
  }
}

// ---------------------------------------------------------------------------
// QKV projection. grid (32, 6, 3): z=0 -> Q(hi,lo), z=1 -> K(hi,lo), z=2 -> V.
// Outputs in [B,H,T,D] layout.
// ---------------------------------------------------------------------------
__global__ __launch_bounds__(256) void qkv_gemm(
    const __hip_bfloat16* __restrict__ Xhi, const __hip_bfloat16* __restrict__ Xlo,
    const __hip_bfloat16* __restrict__ WqThi, const __hip_bfloat16* __restrict__ WqTlo,
    const __hip_bfloat16* __restrict__ WkThi, const __hip_bfloat16* __restrict__ WkTlo,
    const __hip_bfloat16* __restrict__ WvThi,
    __hip_bfloat16* __restrict__ Qhi, __hip_bfloat16* __restrict__ Qlo,
    __hip_bfloat16* __restrict__ Khi, __hip_bfloat16* __restrict__ Klo,
    __hip_bfloat16* __restrict__ V) {
  __shared__ __align__(16) short lds[16384];
  const int z = blockIdx.z;
  const bool lo = (z < 2);
  const __hip_bfloat16* Bhi = (z == 0) ? WqThi : (z == 1) ? WkThi : WvThi;
  const __hip_bfloat16* Blo = (z == 0) ? WqTlo : WkTlo;
  const int m0 = blockIdx.x * 128, n0 = blockIdx.y * 128;

  f32x4 acc[4][4];
#pragma unroll
  for (int i = 0; i < 4; ++i)
#pragma unroll
    for (int j = 0; j < 4; ++j) acc[i][j] = f32x4{0.f, 0.f, 0.f, 0.f};

  gemm128_hilo(Xhi, Xlo, Bhi, Blo, lo, m0, n0, lds, acc);

  const int tid = threadIdx.x, w = tid >> 6, l = tid & 63;
  const int wr = w >> 1, wc = w & 1;
#pragma unroll
  for (int i = 0; i < 4; ++i) {
#pragma unroll
    for (int j = 0; j < 4; ++j) {
#pragma unroll
      for (int r = 0; r < 4; ++r) {
        const int m = m0 + (wr << 6) + (i << 4) + ((l >> 4) << 2) + r;
        const int n = n0 + (wc << 6) + (j << 4) + (l & 15);
        const float v = acc[i][j][r];
        const int b = m >> 11, t = m & 2047, h = n >> 6, d = n & 63;
        const size_t idx = (((size_t)(b * Hh + h)) * Tt + t) * Dd + d;
        if (z == 2) {
          V[idx] = __float2bfloat16(v);
        } else {
          short hbits = f2bfbits(v);
          short lbits = f2bfbits(v - bf2f(hbits));
          if (z == 0) { ((short*)Qhi)[idx] = hbits; ((short*)Qlo)[idx] = lbits; }
          else        { ((short*)Khi)[idx] = hbits; ((short*)Klo)[idx] = lbits; }
        }
      }
    }
  }
}

// ---------------------------------------------------------------------------
// Output projection: out[M,C] (f32) = O[M,C](bf16) * LT[C,C]^T(bf16). grid(32,6)
// ---------------------------------------------------------------------------
__global__ __launch_bounds__(256) void proj_gemm(
    const __hip_bfloat16* __restrict__ O, const __hip_bfloat16* __restrict__ LT,
    float* __restrict__ out) {
  __shared__ __align__(16) short lds[8192];
  const int m0 = blockIdx.x * 128, n0 = blockIdx.y * 128;
  f32x4 acc[4][4];
#pragma unroll
  for (int i = 0; i < 4; ++i)
#pragma unroll
    for (int j = 0; j < 4; ++j) acc[i][j] = f32x4{0.f, 0.f, 0.f, 0.f};

  gemm128_core(O, LT, m0, n0, lds, lds + 4096, acc);

  const int tid = threadIdx.x, w = tid >> 6, l = tid & 63;
  const int wr = w >> 1, wc = w & 1;
#pragma unroll
  for (int i = 0; i < 4; ++i)
#pragma unroll
    for (int j = 0; j < 4; ++j)
#pragma unroll
      for (int r = 0; r < 4; ++r) {
        const int m = m0 + (wr << 6) + (i << 4) + ((l >> 4) << 2) + r;
        const int n = n0 + (wc << 6) + (j << 4) + (l & 15);
        out[(size_t)m * Cc + n] = acc[i][j][r];
      }
}

// ---------------------------------------------------------------------------
// V [BH][T][D] -> VT [BH][D][T].  grid (32, 24), 256 threads.
// ---------------------------------------------------------------------------
__global__ __launch_bounds__(256) void transpose_v(
    const __hip_bfloat16* __restrict__ V, __hip_bfloat16* __restrict__ VT) {
  __shared__ __align__(16) short tile[64][72];
  const int t0 = blockIdx.x * 64, bh = blockIdx.y;
  const __hip_bfloat16* src = V + (size_t)bh * Tt * Dd;
  __hip_bfloat16* dst = VT + (size_t)bh * Dd * Tt;
  const int tid = threadIdx.x;
  const int rr = tid >> 3;
  const int cc = (tid & 7) << 3;
#pragma unroll
  for (int it = 0; it < 2; ++it) {
    const int r = rr + it * 32;
    *reinterpret_cast<s16x8*>(&tile[r][cc]) =
        *reinterpret_cast<const s16x8*>(src + (size_t)(t0 + r) * Dd + cc);
  }
  __syncthreads();
#pragma unroll
  for (int it = 0; it < 2; ++it) {
    const int d = rr + it * 32;
    s16x8 o;
#pragma unroll
    for (int j = 0; j < 8; ++j) o[j] = tile[cc + j][d];
    *reinterpret_cast<s16x8*>(dst + (size_t)d * Tt + t0 + cc) = o;
  }
}

// ---------------------------------------------------------------------------
// Single-fragment (16 q-rows) causal flash pass, swapped-operand layout.
// This is the verified v6 per-qf slice extracted as a function.
// s[kjf][r] = S[k=k0+kjf*16+lg*4+r][q=q0+lr]; oacc[df][r] = O[q=q0+lr][d=df*16+lg*4+r].
// ---------------------------------------------------------------------------
__device__ __forceinline__ void flash16(
    const __hip_bfloat16* __restrict__ qhp, const __hip_bfloat16* __restrict__ qlp,
    const __hip_bfloat16* __restrict__ khp, const __hip_bfloat16* __restrict__ klp,
    const __hip_bfloat16* __restrict__ vtp, short* __restrict__ myP,
    short* __restrict__ obase, int q0, int lr, int lg) {
  s16x8 qh[2], ql[2];
#pragma unroll
  for (int df = 0; df < 2; ++df) {
    const size_t off = (size_t)(q0 + lr) * Dd + df * 32 + lg * 8;
    qh[df] = *reinterpret_cast<const s16x8*>(qhp + off);
    ql[df] = *reinterpret_cast<const s16x8*>(qlp + off);
  }

  f32x4 oacc[4];
#pragma unroll
  for (int df = 0; df < 4; ++df) oacc[df] = f32x4{0.f, 0.f, 0.f, 0.f};
  float mrow = -__builtin_inff(), lrow = 0.f;

  const int ktmax = (q0 + 15) >> 6;
  for (int kt = 0; kt <= ktmax; ++kt) {
    const int k0 = kt << 6;
    const bool dotmask = (k0 + 63) > q0;

    s16x8 kh[4][2], kl[4][2];
#pragma unroll
    for (int kjf = 0; kjf < 4; ++kjf)
#pragma unroll
      for (int df = 0; df < 2; ++df) {
        const size_t off = (size_t)(k0 + kjf * 16 + lr) * Dd + df * 32 + lg * 8;
        kh[kjf][df] = *reinterpret_cast<const s16x8*>(khp + off);
        kl[kjf][df] = *reinterpret_cast<const s16x8*>(klp + off);
      }

    f32x4 s[4];
#pragma unroll
    for (int kjf = 0; kjf < 4; ++kjf) s[kjf] = f32x4{0.f, 0.f, 0.f, 0.f};
#pragma unroll
    for (int kjf = 0; kjf < 4; ++kjf)
#pragma unroll
      for (int df = 0; df < 2; ++df) {
        s[kjf] = MFMA(kh[kjf][df], qh[df], s[kjf]);
        s[kjf] = MFMA(kl[kjf][df], qh[df], s[kjf]);
        s[kjf] = MFMA(kh[kjf][df], ql[df], s[kjf]);
      }

    s16x8 bv[2][4];
#pragma unroll
    for (int kf = 0; kf < 2; ++kf)
#pragma unroll
      for (int df = 0; df < 4; ++df)
        bv[kf][df] = *reinterpret_cast<const s16x8*>(
            vtp + (size_t)(df * 16 + lr) * Tt + k0 + kf * 32 + lg * 8);

    const int q = q0 + lr;
    float mx = -__builtin_inff();
#pragma unroll
    for (int kjf = 0; kjf < 4; ++kjf)
#pragma unroll
      for (int r = 0; r < 4; ++r) {
        float v = s[kjf][r] * 8.0f;
        if (dotmask && (k0 + kjf * 16 + lg * 4 + r) > q) v = -__builtin_inff();
        s[kjf][r] = v;
        mx = fmaxf(mx, v);
      }
    mx = fmaxf(mx, __shfl_xor(mx, 16));
    mx = fmaxf(mx, __shfl_xor(mx, 32));
    const float mnew = fmaxf(mrow, mx);
    const float sc = __expf(mrow - mnew);
    mrow = mnew;
    float ls = 0.f;
#pragma unroll
    for (int kjf = 0; kjf < 4; ++kjf)
#pragma unroll
      for (int r = 0; r < 4; ++r) {
        const float p = __expf(s[kjf][r] - mnew);
        s[kjf][r] = p;
        ls += p;
      }
    ls += __shfl_xor(ls, 16);
    ls += __shfl_xor(ls, 32);
    lrow = lrow * sc + ls;
#pragma unroll
    for (int df = 0; df < 4; ++df) oacc[df] *= sc;

#pragma unroll
    for (int kjf = 0; kjf < 4; ++kjf) {
      uint2 pk;
      pk.x = packbf2(s[kjf][0], s[kjf][1]);
      pk.y = packbf2(s[kjf][2], s[kjf][3]);
      *reinterpret_cast<uint2*>(myP + lr * 72 + kjf * 16 + lg * 4) = pk;
    }

#pragma unroll
    for (int kf = 0; kf < 2; ++kf) {
      const s16x8 pa = *reinterpret_cast<const s16x8*>(myP + lr * 72 + kf * 32 + lg * 8);
#pragma unroll
      for (int df = 0; df < 4; ++df)
        oacc[df] = MFMA(bv[kf][df], pa, oacc[df]);
    }
  }

  const float inv = 1.0f / lrow;
  const int t = q0 + lr;
#pragma unroll
  for (int df = 0; df < 4; ++df) {
    uint2 pk;
    pk.x = packbf2(oacc[df][0] * inv, oacc[df][1] * inv);
    pk.y = packbf2(oacc[df][2] * inv, oacc[df][3] * inv);
    *reinterpret_cast<uint2*>(obase + (size_t)t * Cc + df * 16 + lg * 4) = pk;
  }
}

// ---------------------------------------------------------------------------
// Causal flash attention v7. grid (768) x 128 threads (2 waves).
// Block i: xcd = i&7; j = i>>3 (0..95); bh = (i&7)*3 + j/32.
// Wave w: pp = 2*(j&31) + w in 0..63 -> two sequential passes over
// fragments qA = 16*pp (light) and qB = 2032-16*pp (heavy): 33 tile-units
// per wave, identical for every wave in the grid.
// ---------------------------------------------------------------------------
__global__ __launch_bounds__(128, 2) void attn_fwd(
    const __hip_bfloat16* __restrict__ Qhi, const __hip_bfloat16* __restrict__ Qlo,
    const __hip_bfloat16* __restrict__ Khi, const __hip_bfloat16* __restrict__ Klo,
    const __hip_bfloat16* __restrict__ VT, __hip_bfloat16* __restrict__ O) {
  __shared__ __align__(16) short pbuf[2][16 * 72];
  const int i = blockIdx.x;
  const int j = i >> 3;                       // 0..95
  const int bh = (i & 7) * 3 + (j >> 5);      // 0..23
  const int b = bh / Hh, h = bh % Hh;
  const int tid = threadIdx.x, w = tid >> 6, l = tid & 63;
  const int lr = l & 15, lg = l >> 4;
  const int pp = ((j & 31) << 1) + w;         // 0..63
  const size_t hqk = (size_t)bh * Tt * Dd;
  const __hip_bfloat16* qhp = Qhi + hqk;
  const __hip_bfloat16* qlp = Qlo + hqk;
  const __hip_bfloat16* khp = Khi + hqk;
  const __hip_bfloat16* klp = Klo + hqk;
  const __hip_bfloat16* vtp = VT + (size_t)bh * Dd * Tt;
  short* myP = &pbuf[w][0];
  short* obase = (short*)O + (size_t)b * Tt * Cc + h * Dd;

  flash16(qhp, qlp, khp, klp, vtp, myP, obase, pp << 4, lr, lg);        // light
  flash16(qhp, qlp, khp, klp, vtp, myP, obase, 2032 - (pp << 4), lr, lg); // heavy
}

// ---------------------------------------------------------------------------
extern "C" void kernel_launch(void* const* d_in, const int* in_sizes, int n_in,
                              void* d_out, int out_size, void* d_ws, size_t ws_size,
                              hipStream_t stream) {
  (void)in_sizes; (void)n_in; (void)out_size; (void)ws_size;
  const float* x  = (const float*)d_in[0];
  const float* wq = (const float*)d_in[1];
  const float* wk = (const float*)d_in[2];
  const float* wv = (const float*)d_in[3];
  const float* lm = (const float*)d_in[4];
  float* out = (float*)d_out;
  __hip_bfloat16* ws = (__hip_bfloat16*)d_ws;

  const size_t WSZ = (size_t)Cc * Cc;   // 589824
  const size_t TSZ = (size_t)Mm * Cc;   // 3145728
  __hip_bfloat16* WqThi = ws;
  __hip_bfloat16* WqTlo = WqThi + WSZ;
  __hip_bfloat16* WkThi = WqTlo + WSZ;
  __hip_bfloat16* WkTlo = WkThi + WSZ;
  __hip_bfloat16* WvThi = WkTlo + WSZ;
  __hip_bfloat16* LThi  = WvThi + WSZ;
  __hip_bfloat16* Xhi   = LThi + WSZ;
  __hip_bfloat16* Xlo   = Xhi + TSZ;
  __hip_bfloat16* Qhi   = Xlo + TSZ;
  __hip_bfloat16* Qlo   = Qhi + TSZ;
  __hip_bfloat16* Khi   = Qlo + TSZ;
  __hip_bfloat16* Klo   = Khi + TSZ;
  __hip_bfloat16* Vb    = Klo + TSZ;
  __hip_bfloat16* VT    = Vb + TSZ;
  __hip_bfloat16* Ob    = Vb;          // V dead after transpose_v; reuse for O

  prep_x<<<dim3(Mm * Cc / (256 * 8)), 256, 0, stream>>>(x, Xhi, Xlo);
  prep_w<<<dim3(12, 12, 4), 256, 0, stream>>>(wq, wk, wv, lm,
                                              WqThi, WqTlo, WkThi, WkTlo, WvThi, LThi);
  qkv_gemm<<<dim3(32, 6, 3), 256, 0, stream>>>(Xhi, Xlo, WqThi, WqTlo, WkThi, WkTlo,
                                               WvThi, Qhi, Qlo, Khi, Klo, Vb);
  transpose_v<<<dim3(32, BH), 256, 0, stream>>>(Vb, VT);
  attn_fwd<<<dim3(768), 128, 0, stream>>>(Qhi, Qlo, Khi, Klo, VT, Ob);
  proj_gemm<<<dim3(32, 6), 256, 0, stream>>>(Ob, LThi, out);
}

// Round 9
// 139.819 us; speedup vs baseline: 1.5543x; 1.5543x over previous
//
#include <hip/hip_runtime.h>
#include <hip/hip_bf16.h>

// ---------------------------------------------------------------------------
// MultiHeadedMaskedSelfAttention (B=2,T=2048,C=768,H=12,D=64).
// I/O: float32. Compute: bf16 MFMA with hi/lo compensation on the
// softmax-critical path (x->Q/K and Q.K^T), plain bf16 elsewhere.
// attn_fwd v8: block-cooperative K/V staging via async global_load_lds with
// double-buffered LDS (one barrier per tile; the __syncthreads vmcnt-drain
// overlaps prefetch with compute) + XOR-swizzled LDS layout (pre-swizzled
// global source at stage, ^(lr&7) on ds_read) to kill the 16-way bank
// conflict. 4 waves share each tile; wave w owns q-rows qblk*64+w*16..+15.
// Arithmetic/masks/softmax identical to the verified swapped-operand body.
// Heaviest-first block order (qblk = 31-j) for backfill; 2 blocks/CU.
// ---------------------------------------------------------------------------

typedef float f32x4 __attribute__((ext_vector_type(4)));
typedef short s16x8 __attribute__((ext_vector_type(8)));

#define MFMA(a, b, c) __builtin_amdgcn_mfma_f32_16x16x32_bf16((a), (b), (c), 0, 0, 0)

constexpr int Bb = 2, Tt = 2048, Cc = 768, Hh = 12, Dd = 64;
constexpr int Mm = Bb * Tt;   // 4096
constexpr int BH = Bb * Hh;   // 24

__device__ __forceinline__ void gload16(const void* g, void* l) {
  __builtin_amdgcn_global_load_lds((const __attribute__((address_space(1))) void*)g,
                                   (__attribute__((address_space(3))) void*)l, 16, 0, 0);
}

__device__ __forceinline__ short f2bfbits(float f) {
  __hip_bfloat16 h = __float2bfloat16(f);
  return __builtin_bit_cast(short, h);
}
__device__ __forceinline__ float bf2f(short s) {
  __hip_bfloat16 h = __builtin_bit_cast(__hip_bfloat16, s);
  return __bfloat162float(h);
}
__device__ __forceinline__ unsigned int packbf2(float a, float b) {
  return (unsigned int)(unsigned short)f2bfbits(a) |
         ((unsigned int)(unsigned short)f2bfbits(b) << 16);
}

// ---------------------------------------------------------------------------
// prep_x: x f32 [4096][768] -> Xhi, Xlo bf16. grid(1536), 256 thr, 8 elts/thr.
// ---------------------------------------------------------------------------
__global__ __launch_bounds__(256) void prep_x(const float* __restrict__ x,
                                              __hip_bfloat16* __restrict__ xhi,
                                              __hip_bfloat16* __restrict__ xlo) {
  const size_t i = ((size_t)blockIdx.x * 256 + threadIdx.x) * 8;
  float4 a = *reinterpret_cast<const float4*>(x + i);
  float4 b = *reinterpret_cast<const float4*>(x + i + 4);
  float v[8] = {a.x, a.y, a.z, a.w, b.x, b.y, b.z, b.w};
  s16x8 hi, lo;
#pragma unroll
  for (int j = 0; j < 8; ++j) {
    short h = f2bfbits(v[j]);
    hi[j] = h;
    lo[j] = f2bfbits(v[j] - bf2f(h));
  }
  *reinterpret_cast<s16x8*>((short*)xhi + i) = hi;
  *reinterpret_cast<s16x8*>((short*)xlo + i) = lo;
}

// ---------------------------------------------------------------------------
// prep_w: f32 [768][768] -> transposed bf16. z=0: wq (hi+lo), z=1: wk (hi+lo),
// z=2: wv (hi), z=3: linear (hi). grid (12,12,4), 256 thr, 64x64 tiles.
// ---------------------------------------------------------------------------
__global__ __launch_bounds__(256) void prep_w(
    const float* __restrict__ s0, const float* __restrict__ s1,
    const float* __restrict__ s2, const float* __restrict__ s3,
    __hip_bfloat16* __restrict__ h0, __hip_bfloat16* __restrict__ l0,
    __hip_bfloat16* __restrict__ h1, __hip_bfloat16* __restrict__ l1,
    __hip_bfloat16* __restrict__ h2, __hip_bfloat16* __restrict__ h3) {
  const float* src;
  __hip_bfloat16 *dh, *dl = nullptr;
  switch (blockIdx.z) {
    case 0: src = s0; dh = h0; dl = l0; break;
    case 1: src = s1; dh = h1; dl = l1; break;
    case 2: src = s2; dh = h2; break;
    default: src = s3; dh = h3; break;
  }
  __shared__ float tile[64][65];
  const int r0 = blockIdx.y * 64, c0 = blockIdx.x * 64;
  const int tid = threadIdx.x;
  const int rr = tid >> 4, c4 = (tid & 15) * 4;
#pragma unroll
  for (int it = 0; it < 4; ++it) {
    float4 v = *reinterpret_cast<const float4*>(src + (size_t)(r0 + rr + it * 16) * Cc + c0 + c4);
    tile[rr + it * 16][c4 + 0] = v.x;
    tile[rr + it * 16][c4 + 1] = v.y;
    tile[rr + it * 16][c4 + 2] = v.z;
    tile[rr + it * 16][c4 + 3] = v.w;
  }
  __syncthreads();
#pragma unroll
  for (int it = 0; it < 2; ++it) {
    const int id = tid + it * 256;          // 0..511
    const int n = id >> 3, ch = (id & 7) * 8;
    s16x8 hi, lo;
#pragma unroll
    for (int j = 0; j < 8; ++j) {
      float v = tile[ch + j][n];
      short h = f2bfbits(v);
      hi[j] = h;
      lo[j] = f2bfbits(v - bf2f(h));
    }
    *reinterpret_cast<s16x8*>(dh + (size_t)(c0 + n) * Cc + r0 + ch) = hi;
    if (dl) *reinterpret_cast<s16x8*>(dl + (size_t)(c0 + n) * Cc + r0 + ch) = lo;
  }
}

// ---------------------------------------------------------------------------
// 128x128 GEMM cores. A[M,K] * Bt[N,K]^T, K=768, BK=32, 4 waves.
// ---------------------------------------------------------------------------
__device__ __forceinline__ void gemm128_core(const __hip_bfloat16* __restrict__ A,
                                             const __hip_bfloat16* __restrict__ Bt,
                                             int m0, int n0,
                                             short* ldsA, short* ldsB,
                                             f32x4 acc[4][4]) {
  const int tid = threadIdx.x;
  const int w = tid >> 6, l = tid & 63;
  const int wr = w >> 1, wc = w & 1;
  const int srow = l >> 2;
  const int scol = (l & 3) << 3;

  for (int kt = 0; kt < Cc / 32; ++kt) {
    const int kk = kt << 5;
#pragma unroll
    for (int i = 0; i < 2; ++i) {
      const int r = (w << 5) + (i << 4);
      gload16(A + (size_t)(m0 + r + srow) * Cc + kk + scol, ldsA + r * 32);
      gload16(Bt + (size_t)(n0 + r + srow) * Cc + kk + scol, ldsB + r * 32);
    }
    __syncthreads();
    s16x8 af[4], bfr[4];
#pragma unroll
    for (int i = 0; i < 4; ++i) {
      af[i]  = *reinterpret_cast<const s16x8*>(ldsA + ((wr << 6) + (i << 4) + (l & 15)) * 32 + ((l >> 4) << 3));
      bfr[i] = *reinterpret_cast<const s16x8*>(ldsB + ((wc << 6) + (i << 4) + (l & 15)) * 32 + ((l >> 4) << 3));
    }
#pragma unroll
    for (int i = 0; i < 4; ++i)
#pragma unroll
      for (int j = 0; j < 4; ++j)
        acc[i][j] = MFMA(af[i], bfr[j], acc[i][j]);
    __syncthreads();
  }
}

// hi/lo compensated: acc += Ahi*Bhi + (lo ? Ahi*Blo + Alo*Bhi : 0)
__device__ __forceinline__ void gemm128_hilo(
    const __hip_bfloat16* __restrict__ Ahi, const __hip_bfloat16* __restrict__ Alo,
    const __hip_bfloat16* __restrict__ Bhi, const __hip_bfloat16* __restrict__ Blo,
    bool lo, int m0, int n0, short* lds, f32x4 acc[4][4]) {
  short* ldsAh = lds;
  short* ldsAl = lds + 4096;
  short* ldsBh = lds + 8192;
  short* ldsBl = lds + 12288;
  const int tid = threadIdx.x;
  const int w = tid >> 6, l = tid & 63;
  const int wr = w >> 1, wc = w & 1;
  const int srow = l >> 2;
  const int scol = (l & 3) << 3;

  for (int kt = 0; kt < Cc / 32; ++kt) {
    const int kk = kt << 5;
#pragma unroll
    for (int i = 0; i < 2; ++i) {
      const int r = (w << 5) + (i << 4);
      const size_t aoff = (size_t)(m0 + r + srow) * Cc + kk + scol;
      const size_t boff = (size_t)(n0 + r + srow) * Cc + kk + scol;
      gload16(Ahi + aoff, ldsAh + r * 32);
      gload16(Bhi + boff, ldsBh + r * 32);
      if (lo) {
        gload16(Alo + aoff, ldsAl + r * 32);
        gload16(Blo + boff, ldsBl + r * 32);
      }
    }
    __syncthreads();
    s16x8 ah[4], bh[4], al[4], bl[4];
#pragma unroll
    for (int i = 0; i < 4; ++i) {
      const int ao = ((wr << 6) + (i << 4) + (l & 15)) * 32 + ((l >> 4) << 3);
      const int bo = ((wc << 6) + (i << 4) + (l & 15)) * 32 + ((l >> 4) << 3);
      ah[i] = *reinterpret_cast<const s16x8*>(ldsAh + ao);
      bh[i] = *reinterpret_cast<const s16x8*>(ldsBh + bo);
      if (lo) {
        al[i] = *reinterpret_cast<const s16x8*>(ldsAl + ao);
        bl[i] = *reinterpret_cast<const s16x8*>(ldsBl + bo);
      }
    }
#pragma unroll
    for (int i = 0; i < 4; ++i)
#pragma unroll
      for (int j = 0; j < 4; ++j)
        acc[i][j] = MFMA(ah[i], bh[j], acc[i][j]);
    if (lo) {
#pragma unroll
      for (int i = 0; i < 4; ++i)
#pragma unroll
        for (int j = 0; j < 4; ++j) {
          acc[i][j] = MFMA(ah[i], bl[j], acc[i][j]);
          acc[i][j] = MFMA(al[i], bh[j], acc[i][j]);
        }
    }
    __syncthreads();
  }
}

// ---------------------------------------------------------------------------
// QKV projection. grid (32, 6, 3): z=0 -> Q(hi,lo), z=1 -> K(hi,lo), z=2 -> V.
// Outputs in [B,H,T,D] layout.
// ---------------------------------------------------------------------------
__global__ __launch_bounds__(256) void qkv_gemm(
    const __hip_bfloat16* __restrict__ Xhi, const __hip_bfloat16* __restrict__ Xlo,
    const __hip_bfloat16* __restrict__ WqThi, const __hip_bfloat16* __restrict__ WqTlo,
    const __hip_bfloat16* __restrict__ WkThi, const __hip_bfloat16* __restrict__ WkTlo,
    const __hip_bfloat16* __restrict__ WvThi,
    __hip_bfloat16* __restrict__ Qhi, __hip_bfloat16* __restrict__ Qlo,
    __hip_bfloat16* __restrict__ Khi, __hip_bfloat16* __restrict__ Klo,
    __hip_bfloat16* __restrict__ V) {
  __shared__ __align__(16) short lds[16384];
  const int z = blockIdx.z;
  const bool lo = (z < 2);
  const __hip_bfloat16* Bhi = (z == 0) ? WqThi : (z == 1) ? WkThi : WvThi;
  const __hip_bfloat16* Blo = (z == 0) ? WqTlo : WkTlo;
  const int m0 = blockIdx.x * 128, n0 = blockIdx.y * 128;

  f32x4 acc[4][4];
#pragma unroll
  for (int i = 0; i < 4; ++i)
#pragma unroll
    for (int j = 0; j < 4; ++j) acc[i][j] = f32x4{0.f, 0.f, 0.f, 0.f};

  gemm128_hilo(Xhi, Xlo, Bhi, Blo, lo, m0, n0, lds, acc);

  const int tid = threadIdx.x, w = tid >> 6, l = tid & 63;
  const int wr = w >> 1, wc = w & 1;
#pragma unroll
  for (int i = 0; i < 4; ++i) {
#pragma unroll
    for (int j = 0; j < 4; ++j) {
#pragma unroll
      for (int r = 0; r < 4; ++r) {
        const int m = m0 + (wr << 6) + (i << 4) + ((l >> 4) << 2) + r;
        const int n = n0 + (wc << 6) + (j << 4) + (l & 15);
        const float v = acc[i][j][r];
        const int b = m >> 11, t = m & 2047, h = n >> 6, d = n & 63;
        const size_t idx = (((size_t)(b * Hh + h)) * Tt + t) * Dd + d;
        if (z == 2) {
          V[idx] = __float2bfloat16(v);
        } else {
          short hbits = f2bfbits(v);
          short lbits = f2bfbits(v - bf2f(hbits));
          if (z == 0) { ((short*)Qhi)[idx] = hbits; ((short*)Qlo)[idx] = lbits; }
          else        { ((short*)Khi)[idx] = hbits; ((short*)Klo)[idx] = lbits; }
        }
      }
    }
  }
}

// ---------------------------------------------------------------------------
// Output projection: out[M,C] (f32) = O[M,C](bf16) * LT[C,C]^T(bf16). grid(32,6)
// ---------------------------------------------------------------------------
__global__ __launch_bounds__(256) void proj_gemm(
    const __hip_bfloat16* __restrict__ O, const __hip_bfloat16* __restrict__ LT,
    float* __restrict__ out) {
  __shared__ __align__(16) short lds[8192];
  const int m0 = blockIdx.x * 128, n0 = blockIdx.y * 128;
  f32x4 acc[4][4];
#pragma unroll
  for (int i = 0; i < 4; ++i)
#pragma unroll
    for (int j = 0; j < 4; ++j) acc[i][j] = f32x4{0.f, 0.f, 0.f, 0.f};

  gemm128_core(O, LT, m0, n0, lds, lds + 4096, acc);

  const int tid = threadIdx.x, w = tid >> 6, l = tid & 63;
  const int wr = w >> 1, wc = w & 1;
#pragma unroll
  for (int i = 0; i < 4; ++i)
#pragma unroll
    for (int j = 0; j < 4; ++j)
#pragma unroll
      for (int r = 0; r < 4; ++r) {
        const int m = m0 + (wr << 6) + (i << 4) + ((l >> 4) << 2) + r;
        const int n = n0 + (wc << 6) + (j << 4) + (l & 15);
        out[(size_t)m * Cc + n] = acc[i][j][r];
      }
}

// ---------------------------------------------------------------------------
// V [BH][T][D] -> VT [BH][D][T].  grid (32, 24), 256 threads.
// ---------------------------------------------------------------------------
__global__ __launch_bounds__(256) void transpose_v(
    const __hip_bfloat16* __restrict__ V, __hip_bfloat16* __restrict__ VT) {
  __shared__ __align__(16) short tile[64][72];
  const int t0 = blockIdx.x * 64, bh = blockIdx.y;
  const __hip_bfloat16* src = V + (size_t)bh * Tt * Dd;
  __hip_bfloat16* dst = VT + (size_t)bh * Dd * Tt;
  const int tid = threadIdx.x;
  const int rr = tid >> 3;
  const int cc = (tid & 7) << 3;
#pragma unroll
  for (int it = 0; it < 2; ++it) {
    const int r = rr + it * 32;
    *reinterpret_cast<s16x8*>(&tile[r][cc]) =
        *reinterpret_cast<const s16x8*>(src + (size_t)(t0 + r) * Dd + cc);
  }
  __syncthreads();
#pragma unroll
  for (int it = 0; it < 2; ++it) {
    const int d = rr + it * 32;
    s16x8 o;
#pragma unroll
    for (int j = 0; j < 8; ++j) o[j] = tile[cc + j][d];
    *reinterpret_cast<s16x8*>(dst + (size_t)d * Tt + t0 + cc) = o;
  }
}

// ---------------------------------------------------------------------------
// Causal flash attention v8. grid (768) x 256 threads (4 waves).
// Block i: xcd = i&7; j = i>>3 (0..95); bh = (i&7)*3 + j/32; qblk = 31-(j&31)
// (heaviest first). Wave w owns q-rows q0 = qblk*64 + w*16 .. +15.
// Per tile: 24 async global_load_lds issues (Khi, Klo, V; 8 each, split 6
// per wave) into double-buffered LDS with XOR-swizzled layout:
//   LDS[row][g] = G[row][g ^ (row&7)]  (16B col-groups g=0..7)
// staged via pre-swizzled per-lane source col-group (l&7)^(l>>3);
// ds_read uses group (want ^ (row&7)). One __syncthreads per tile drains
// vmcnt (prefetch overlaps compute). Math identical to verified v6/v7 body.
// ---------------------------------------------------------------------------
__global__ __launch_bounds__(256, 2) void attn_fwd(
    const __hip_bfloat16* __restrict__ Qhi, const __hip_bfloat16* __restrict__ Qlo,
    const __hip_bfloat16* __restrict__ Khi, const __hip_bfloat16* __restrict__ Klo,
    const __hip_bfloat16* __restrict__ VT, __hip_bfloat16* __restrict__ O) {
  __shared__ __align__(16) short kv[2][3][4096];   // [buf][Khi,Klo,V][64x64]
  __shared__ __align__(16) short pbuf[4][16 * 72];
  const int i = blockIdx.x;
  const int j = i >> 3;                        // 0..95
  const int bh = (i & 7) * 3 + (j >> 5);       // 0..23 (3 heads per XCD)
  const int qblk = 31 - (j & 31);              // heaviest blocks first
  const int b = bh / Hh, h = bh % Hh;
  const int tid = threadIdx.x, w = tid >> 6, l = tid & 63;
  const int lr = l & 15, lg = l >> 4;
  const int q0 = qblk * 64 + w * 16;           // this wave's 16 q-rows
  const size_t hqk = (size_t)bh * Tt * Dd;
  const __hip_bfloat16* qhp = Qhi + hqk;
  const __hip_bfloat16* qlp = Qlo + hqk;
  const __hip_bfloat16* khp = Khi + hqk;
  const __hip_bfloat16* klp = Klo + hqk;
  const __hip_bfloat16* vtp = VT + (size_t)bh * Dd * Tt;
  short* myP = &pbuf[w][0];
  short* obase = (short*)O + (size_t)b * Tt * Cc + h * Dd;

  // staging constants: issue covers rows i2*8..i2*8+7; lane l -> row i2*8+rr,
  // LDS col-group l&7, global col-group gg = (l&7)^rr  (pre-swizzle)
  const int rr = l >> 3;
  const int gg = (l & 7) ^ rr;

  // stage one 64x64 tile triple (Khi,Klo,V) into kv[buf]; 6 issues per wave
  auto stage = [&](int buf, int k0) {
#pragma unroll
    for (int s6 = 0; s6 < 6; ++s6) {
      const int s = w * 6 + s6;                // 0..23
      const int m = s >> 3, i2 = s & 7;
      const int row = i2 * 8 + rr;
      const __hip_bfloat16* src =
          (m == 0) ? khp + (size_t)(k0 + row) * Dd + gg * 8
        : (m == 1) ? klp + (size_t)(k0 + row) * Dd + gg * 8
                   : vtp + (size_t)row * Tt + k0 + gg * 8;
      gload16(src, &kv[buf][m][i2 * 512]);
    }
  };

  stage(0, 0);

  // Q fragments (B-operand: col = lr = q), direct global (one-time)
  s16x8 qh[2], ql[2];
#pragma unroll
  for (int df = 0; df < 2; ++df) {
    const size_t off = (size_t)(q0 + lr) * Dd + df * 32 + lg * 8;
    qh[df] = *reinterpret_cast<const s16x8*>(qhp + off);
    ql[df] = *reinterpret_cast<const s16x8*>(qlp + off);
  }

  f32x4 oacc[4];
#pragma unroll
  for (int df = 0; df < 4; ++df) oacc[df] = f32x4{0.f, 0.f, 0.f, 0.f};
  float mrow = -__builtin_inff(), lrow = 0.f;

  __syncthreads();                             // tile-0 staged (drains vmcnt)

  const int sw = lr & 7;                       // read-side swizzle key
  for (int kt = 0; kt <= qblk; ++kt) {
    const int cur = kt & 1;
    const int k0 = kt << 6;
    if (kt < qblk) stage(cur ^ 1, (kt + 1) << 6);   // prefetch next tile

    const short* Kh = &kv[cur][0][0];
    const short* Kl = &kv[cur][1][0];
    const short* Vv = &kv[cur][2][0];
    const bool dotmask = (k0 + 63) > q0;

    // --- S^T = K Q^T (swapped; hi/lo compensated), K frags from LDS ---
    f32x4 s[4];
#pragma unroll
    for (int kjf = 0; kjf < 4; ++kjf) s[kjf] = f32x4{0.f, 0.f, 0.f, 0.f};
#pragma unroll
    for (int kjf = 0; kjf < 4; ++kjf)
#pragma unroll
      for (int df = 0; df < 2; ++df) {
        const int off = (kjf * 16 + lr) * 64 + (((df * 4 + lg) ^ sw) << 3);
        const s16x8 kh = *reinterpret_cast<const s16x8*>(Kh + off);
        const s16x8 kl = *reinterpret_cast<const s16x8*>(Kl + off);
        s[kjf] = MFMA(kh, qh[df], s[kjf]);
        s[kjf] = MFMA(kl, qh[df], s[kjf]);
        s[kjf] = MFMA(kh, ql[df], s[kjf]);
      }

    // --- in-register online softmax (verified body) ---
    const int q = q0 + lr;
    float mx = -__builtin_inff();
#pragma unroll
    for (int kjf = 0; kjf < 4; ++kjf)
#pragma unroll
      for (int r = 0; r < 4; ++r) {
        float v = s[kjf][r] * 8.0f;
        if (dotmask && (k0 + kjf * 16 + lg * 4 + r) > q) v = -__builtin_inff();
        s[kjf][r] = v;
        mx = fmaxf(mx, v);
      }
    mx = fmaxf(mx, __shfl_xor(mx, 16));
    mx = fmaxf(mx, __shfl_xor(mx, 32));
    const float mnew = fmaxf(mrow, mx);
    const float sc = __expf(mrow - mnew);
    mrow = mnew;
    float ls = 0.f;
#pragma unroll
    for (int kjf = 0; kjf < 4; ++kjf)
#pragma unroll
      for (int r = 0; r < 4; ++r) {
        const float p = __expf(s[kjf][r] - mnew);
        s[kjf][r] = p;
        ls += p;
      }
    ls += __shfl_xor(ls, 16);
    ls += __shfl_xor(ls, 32);
    lrow = lrow * sc + ls;
#pragma unroll
    for (int df = 0; df < 4; ++df) oacc[df] *= sc;

    // --- P -> LDS as [q][k] bf16 (packed b64 writes), wave-private ---
#pragma unroll
    for (int kjf = 0; kjf < 4; ++kjf) {
      uint2 pk;
      pk.x = packbf2(s[kjf][0], s[kjf][1]);
      pk.y = packbf2(s[kjf][2], s[kjf][3]);
      *reinterpret_cast<uint2*>(myP + lr * 72 + kjf * 16 + lg * 4) = pk;
    }

    // --- O^T += V^T P^T, V frags from LDS ---
#pragma unroll
    for (int kf = 0; kf < 2; ++kf) {
      const s16x8 pa = *reinterpret_cast<const s16x8*>(myP + lr * 72 + kf * 32 + lg * 8);
#pragma unroll
      for (int df = 0; df < 4; ++df) {
        const int off = (df * 16 + lr) * 64 + (((kf * 4 + lg) ^ sw) << 3);
        const s16x8 bv = *reinterpret_cast<const s16x8*>(Vv + off);
        oacc[df] = MFMA(bv, pa, oacc[df]);
      }
    }

    __syncthreads();   // all waves done with kv[cur]; prefetch drained (vmcnt0)
  }

  // --- epilogue: O[b][t=q][h*64+d], d = df*16+lg*4+r, packed 8B stores ---
  const float inv = 1.0f / lrow;
  const int t = q0 + lr;
#pragma unroll
  for (int df = 0; df < 4; ++df) {
    uint2 pk;
    pk.x = packbf2(oacc[df][0] * inv, oacc[df][1] * inv);
    pk.y = packbf2(oacc[df][2] * inv, oacc[df][3] * inv);
    *reinterpret_cast<uint2*>(obase + (size_t)t * Cc + df * 16 + lg * 4) = pk;
  }
}

// ---------------------------------------------------------------------------
extern "C" void kernel_launch(void* const* d_in, const int* in_sizes, int n_in,
                              void* d_out, int out_size, void* d_ws, size_t ws_size,
                              hipStream_t stream) {
  (void)in_sizes; (void)n_in; (void)out_size; (void)ws_size;
  const float* x  = (const float*)d_in[0];
  const float* wq = (const float*)d_in[1];
  const float* wk = (const float*)d_in[2];
  const float* wv = (const float*)d_in[3];
  const float* lm = (const float*)d_in[4];
  float* out = (float*)d_out;
  __hip_bfloat16* ws = (__hip_bfloat16*)d_ws;

  const size_t WSZ = (size_t)Cc * Cc;   // 589824
  const size_t TSZ = (size_t)Mm * Cc;   // 3145728
  __hip_bfloat16* WqThi = ws;
  __hip_bfloat16* WqTlo = WqThi + WSZ;
  __hip_bfloat16* WkThi = WqTlo + WSZ;
  __hip_bfloat16* WkTlo = WkThi + WSZ;
  __hip_bfloat16* WvThi = WkTlo + WSZ;
  __hip_bfloat16* LThi  = WvThi + WSZ;
  __hip_bfloat16* Xhi   = LThi + WSZ;
  __hip_bfloat16* Xlo   = Xhi + TSZ;
  __hip_bfloat16* Qhi   = Xlo + TSZ;
  __hip_bfloat16* Qlo   = Qhi + TSZ;
  __hip_bfloat16* Khi   = Qlo + TSZ;
  __hip_bfloat16* Klo   = Khi + TSZ;
  __hip_bfloat16* Vb    = Klo + TSZ;
  __hip_bfloat16* VT    = Vb + TSZ;
  __hip_bfloat16* Ob    = Vb;          // V dead after transpose_v; reuse for O

  prep_x<<<dim3(Mm * Cc / (256 * 8)), 256, 0, stream>>>(x, Xhi, Xlo);
  prep_w<<<dim3(12, 12, 4), 256, 0, stream>>>(wq, wk, wv, lm,
                                              WqThi, WqTlo, WkThi, WkTlo, WvThi, LThi);
  qkv_gemm<<<dim3(32, 6, 3), 256, 0, stream>>>(Xhi, Xlo, WqThi, WqTlo, WkThi, WkTlo,
                                               WvThi, Qhi, Qlo, Khi, Klo, Vb);
  transpose_v<<<dim3(32, BH), 256, 0, stream>>>(Vb, VT);
  attn_fwd<<<dim3(768), 256, 0, stream>>>(Qhi, Qlo, Khi, Klo, VT, Ob);
  proj_gemm<<<dim3(32, 6), 256, 0, stream>>>(Ob, LThi, out);
}